// Round 16
// baseline (436.319 us; speedup 1.0000x reference)
//
#include <hip/hip_runtime.h>
#include <hip/hip_bf16.h>
#include <math.h>

#define N_NODES 50000
#define N_EDGES 800000
#define N_GRAPH 128
#define F_IN    1024
#define D_HID   128
#define NT3     (3*N_NODES)
#define LOG2E   1.44269504f

// bucketed CSR build
#define NPB_SH  9
#define NPB     512
#define NB      ((NT3 + NPB - 1) / NPB)   // 293
#define CAP     10240
#define EPB     4096
#define NBIN_PB ((3*N_EDGES + EPB - 1) / EPB)   // 586 blocks per branch

typedef __bf16 bf16x8 __attribute__((ext_vector_type(8)));
typedef float  f32x4  __attribute__((ext_vector_type(4)));
typedef float  f32x2  __attribute__((ext_vector_type(2)));
typedef ushort u16x8  __attribute__((ext_vector_type(8)));

__device__ __forceinline__ float lrelu01(float x){ return x > 0.f ? x : 0.01f*x; }
__device__ __forceinline__ float lrelu02(float x){ return x > 0.f ? x : 0.2f*x; }
__device__ __forceinline__ ushort f2bf(float v){
    __hip_bfloat16 hb = __float2bfloat16(v);
    return *reinterpret_cast<ushort*>(&hb);
}
__device__ __forceinline__ unsigned char f2fp8(float v){
    return (unsigned char)(__builtin_amdgcn_cvt_pk_fp8_f32(v, v, 0, false) & 0xFF);
}
__device__ __forceinline__ bf16x8 cvt8(float4 a, float4 b){
    u16x8 u;
    u[0]=f2bf(a.x); u[1]=f2bf(a.y); u[2]=f2bf(a.z); u[3]=f2bf(a.w);
    u[4]=f2bf(b.x); u[5]=f2bf(b.y); u[6]=f2bf(b.z); u[7]=f2bf(b.w);
    return *reinterpret_cast<bf16x8*>(&u);
}
// async 16B global -> LDS (wave-uniform lds base; HW adds lane*16)
__device__ __forceinline__ void gload16(const void* g, void* l){
    __builtin_amdgcn_global_load_lds((const __attribute__((address_space(1))) unsigned int*)g,
                                     (__attribute__((address_space(3))) unsigned int*)l, 16, 0, 0);
}
// acc2[0..3] += w2 * fp8x8 (one uint2), packed f32x2 math
__device__ __forceinline__ void fma8pk(uint2 u, f32x2 w2, f32x2* acc2){
    acc2[0] += w2 * __builtin_amdgcn_cvt_pk_f32_fp8(u.x, false);
    acc2[1] += w2 * __builtin_amdgcn_cvt_pk_f32_fp8(u.x, true);
    acc2[2] += w2 * __builtin_amdgcn_cvt_pk_f32_fp8(u.y, false);
    acc2[3] += w2 * __builtin_amdgcn_cvt_pk_f32_fp8(u.y, true);
}

// ---------- prep: cast both W's to Wt[2][128][1024] bf16 + zero gcur ----------
__global__ void k_prep(const float* __restrict__ W0, const float* __restrict__ W1,
                       ushort* __restrict__ Wt, int* __restrict__ gcur){
    int b = blockIdx.x, t = threadIdx.x;
    if (b < 1024){
        int idx = b*256 + t;              // 0 .. 262143
        int br  = idx >> 17;              // 131072 per branch
        int r   = idx & 131071;
        int n = r >> 10, k = r & 1023;
        const float* W = br ? W1 : W0;
        Wt[idx] = f2bf(W[k*D_HID + n]);
    } else {
        for (int i=t; i<2*NB; i+=256) gcur[i] = 0;
    }
}

// ---------- GEMM: global_load_lds dbuf staging (BK=32), swizzled LDS, fp8 H out ----------
#define BM   64
#define BKG  32

__global__ __launch_bounds__(256) void k_gemm(const float* __restrict__ X0, const float* __restrict__ X1,
                                              const ushort* __restrict__ Wt,
                                              const float* __restrict__ as0, const float* __restrict__ ad0,
                                              const float* __restrict__ as1, const float* __restrict__ ad1,
                                              unsigned char* __restrict__ H8,
                                              float* __restrict__ als, float* __restrict__ ald){
    __shared__ __align__(16) float  Asl[2][2048];   // 64 rows x 32 f32, swizzled 16B chunks
    __shared__ __align__(16) ushort Bsl[2][4096];   // 128 rows x 32 bf16, swizzled 16B chunks
    __shared__ float alp[4][2][64];
    int br = blockIdx.y;
    const float*  X   = br ? X1 : X0;
    const float*  asr = br ? as1 : as0;
    const float*  adr = br ? ad1 : ad0;
    const ushort* Wtb = Wt + (size_t)br*D_HID*F_IN;
    unsigned char* Hbb = H8 + (size_t)br*N_NODES*D_HID;

    int tid  = threadIdx.x;
    int m0   = blockIdx.x * BM;
    int lane = tid & 63;
    int wave = tid >> 6;
    int l15 = lane & 15, l4 = lane >> 4;
    int wcol = wave * 32;

    auto issue = [&](int kt, int buf){
        // A: 8KB, 2 instrs/wave; lds off o = wave*2048 + j*1024 + lane*16
        #pragma unroll
        for (int j=0;j<2;j++){
            int o = wave*2048 + j*1024 + lane*16;
            int row = o >> 7, chunk = (o >> 4) & 7;
            int grow = min(m0 + row, N_NODES-1);
            const float* g = X + (size_t)grow*F_IN + kt + ((chunk ^ (row & 7)) << 2);
            gload16(g, (char*)&Asl[buf][0] + wave*2048 + j*1024);
        }
        // B: 8KB, 2 instrs/wave
        #pragma unroll
        for (int j=0;j<2;j++){
            int o = wave*2048 + j*1024 + lane*16;
            int row = o >> 6, chunk = (o >> 4) & 3;
            const ushort* g = Wtb + (size_t)row*F_IN + kt + ((chunk ^ ((row >> 1) & 3)) << 3);
            gload16(g, (char*)&Bsl[buf][0] + wave*2048 + j*1024);
        }
    };

    f32x4 acc[4][2];
    #pragma unroll
    for (int i=0;i<4;i++) for (int j=0;j<2;j++) acc[i][j] = (f32x4){0.f,0.f,0.f,0.f};

    issue(0, 0);
    __syncthreads();                      // drains vmcnt -> tile0 in LDS

    const int NT = F_IN / BKG;            // 32
    for (int t = 0; t < NT; ++t){
        int cur = t & 1;
        if (t + 1 < NT) issue((t+1)*BKG, cur ^ 1);
        bf16x8 af[4], bfr[2];
        #pragma unroll
        for (int mi=0;mi<4;mi++){
            int row = mi*16 + l15;
            const char* base = (const char*)&Asl[cur][0] + row*128;
            float4 a0 = *(const float4*)(base + ((( 2*l4   ) ^ (row & 7)) << 4));
            float4 a1 = *(const float4*)(base + (((2*l4 + 1) ^ (row & 7)) << 4));
            af[mi] = cvt8(a0, a1);
        }
        #pragma unroll
        for (int ni=0;ni<2;ni++){
            int row = wcol + ni*16 + l15;
            bfr[ni] = *(const bf16x8*)((const char*)&Bsl[cur][0] + row*64 + ((l4 ^ ((l15 >> 1) & 3)) << 4));
        }
        #pragma unroll
        for (int mi=0;mi<4;mi++)
            #pragma unroll
            for (int ni=0;ni<2;ni++)
                acc[mi][ni] = __builtin_amdgcn_mfma_f32_16x16x32_bf16(af[mi], bfr[ni], acc[mi][ni], 0,0,0);
        __syncthreads();                  // frees buf[cur]; completes tile t+1 loads
    }

    // epilogue: fp8 H write + fused al_s/al_d
    float asv[2], adv[2];
    #pragma unroll
    for (int ni=0;ni<2;ni++){
        int c = wcol + ni*16 + l15;
        asv[ni] = asr[c]; adv[ni] = adr[c];
    }
    #pragma unroll
    for (int mi=0;mi<4;mi++){
        #pragma unroll
        for (int jj=0;jj<4;jj++){
            int rrel = mi*16 + l4*4 + jj;
            int r = m0 + rrel;
            float ps = 0.f, pd = 0.f;
            #pragma unroll
            for (int ni=0;ni<2;ni++){
                float v = acc[mi][ni][jj];
                ps += v*asv[ni]; pd += v*adv[ni];
                if (r < N_NODES){
                    int c = wcol + ni*16 + l15;
                    Hbb[(size_t)r*D_HID + c] = f2fp8(v);
                }
            }
            #pragma unroll
            for (int o=1;o<16;o<<=1){ ps += __shfl_xor(ps,o); pd += __shfl_xor(pd,o); }
            if (l15 == 0){ alp[wave][0][rrel] = ps; alp[wave][1][rrel] = pd; }
        }
    }
    __syncthreads();
    if (tid < 64){
        int r = m0 + tid;
        if (r < N_NODES){
            float s_ = alp[0][0][tid]+alp[1][0][tid]+alp[2][0][tid]+alp[3][0][tid];
            float d_ = alp[0][1][tid]+alp[1][1][tid]+alp[2][1][tid]+alp[3][1][tid];
            als[br*N_NODES + r] = s_;
            ald[br*N_NODES + r] = d_;
        }
    }
}

// ---------- bucketed CSR: bin (both branches) ----------
__global__ __launch_bounds__(256) void k_bin(const int* __restrict__ e10, const int* __restrict__ e20,
                                             const int* __restrict__ e30,
                                             const int* __restrict__ e11, const int* __restrict__ e21,
                                             const int* __restrict__ e31,
                                             int* __restrict__ gcur, uint* __restrict__ pairs){
    __shared__ int hist[NB];
    __shared__ int start[NB];
    int blk = blockIdx.x;
    int br    = blk / NBIN_PB;
    int chunk = blk - br*NBIN_PB;
    int tid = threadIdx.x;
    for (int b=tid; b<NB; b+=256) hist[b]=0;
    __syncthreads();
    long base = (long)chunk * EPB;
    int  myb[16]; uint mypk[16];
    #pragma unroll
    for (int i=0;i<16;i++){
        long idx = base + i*256 + tid;
        int b = -1; uint pk = 0;
        if (idx < 3L*N_EDGES){
            int hop = (idx >= 2L*N_EDGES) ? 2 : (idx >= (long)N_EDGES) ? 1 : 0;
            int e   = (int)(idx - (long)hop*N_EDGES);
            const int* ei = (br==0) ? ((hop==0)?e10:(hop==1)?e20:e30)
                                    : ((hop==0)?e11:(hop==1)?e21:e31);
            int src = ei[e];
            int vd  = hop*N_NODES + ei[N_EDGES + e];
            b   = vd >> NPB_SH;
            pk  = (uint)src | ((uint)(vd & (NPB-1)) << 16);
            atomicAdd(&hist[b], 1);
        }
        myb[i]=b; mypk[i]=pk;
    }
    __syncthreads();
    for (int b=tid; b<NB; b+=256){
        int h = hist[b];
        start[b] = (h>0) ? atomicAdd(&gcur[br*NB + b], h) : 0;
    }
    __syncthreads();
    for (int b=tid; b<NB; b+=256) hist[b] = start[b];
    __syncthreads();
    #pragma unroll
    for (int i=0;i<16;i++){
        int b = myb[i];
        if (b >= 0){
            int pos = atomicAdd(&hist[b], 1);
            if (pos < CAP) pairs[((size_t)(br*NB + b))*CAP + pos] = mypk[i];
        }
    }
}

// ---------- localcsr: per-block inline bucket prefix + local scan/fill ----------
__global__ __launch_bounds__(256) void k_localcsr(const int* __restrict__ gcur,
                                                  const uint* __restrict__ pairs,
                                                  int* __restrict__ offs3, int* __restrict__ esrc){
    __shared__ int sc[512];
    __shared__ int deg[NPB];
    __shared__ int cur[NPB];
    __shared__ int ss[256];
    int gb = blockIdx.x;
    int br = gb / NB, bb = gb - br*NB;
    int t = threadIdx.x;
    sc[t]     = (t < NB)       ? min(gcur[br*NB + t], CAP) : 0;
    sc[t+256] = (t+256 < NB)   ? min(gcur[br*NB + t+256], CAP) : 0;
    __syncthreads();
    for (int o=1;o<512;o<<=1){
        int v0 = (t>=o)     ? sc[t-o]     : 0;
        int v1 = (t+256>=o) ? sc[t+256-o] : 0;
        __syncthreads();
        sc[t] += v0; sc[t+256] += v1;
        __syncthreads();
    }
    int base = (bb==0) ? 0 : sc[bb-1];
    int cnt  = sc[bb] - base;
    int* offsb = offs3 + (size_t)br*(NT3+1);
    if (bb == NB-1 && t == 0) offsb[NT3] = sc[NB-1];

    deg[t]=0; deg[t+256]=0;
    __syncthreads();
    const uint* pbuf = pairs + ((size_t)(br*NB + bb))*CAP;
    for (int i=t; i<cnt; i+=256) atomicAdd(&deg[pbuf[i] >> 16], 1);
    __syncthreads();
    int a0 = deg[2*t], a1 = deg[2*t+1];
    int ps = a0 + a1;
    ss[t] = ps; __syncthreads();
    for (int o=1;o<256;o<<=1){
        int u = (t>=o) ? ss[t-o] : 0;
        __syncthreads(); ss[t] += u; __syncthreads();
    }
    int ex = ss[t] - ps;
    __syncthreads();
    deg[2*t] = ex; deg[2*t+1] = ex + a0;
    cur[2*t] = ex; cur[2*t+1] = ex + a0;
    __syncthreads();
    int vd0 = bb << NPB_SH;
    for (int l=t; l<NPB; l+=256){
        int vd = vd0 + l;
        if (vd < NT3) offsb[vd] = base + deg[l];
    }
    int* esrcb = esrc + (size_t)br*3*N_EDGES;
    for (int i=t; i<cnt; i+=256){
        uint p = pbuf[i];
        int pos = atomicAdd(&cur[p >> 16], 1);
        esrcb[base + pos] = (int)(p & 0xFFFFu);
    }
}

// ---------- GAT aggregate: fp8 rows, 4x16-lane groups, unroll-2, pk-FMA ----------
__global__ __launch_bounds__(256) void k_gat3(const int* __restrict__ offs3, const int* __restrict__ esrc3,
                     const float* __restrict__ als, const float* __restrict__ ald,
                     const uint2* __restrict__ H8,
                     const float* __restrict__ bv0, const float* __restrict__ bv1,
                     float* __restrict__ hacc){
    __shared__ uint2 sh[4][64];
    int br = blockIdx.y;
    const int*   offs = offs3 + (size_t)br*(NT3+1);
    const int*   esrc = esrc3 + (size_t)br*3*N_EDGES;
    const float* alsb = als + br*N_NODES;
    const float* aldb = ald + br*N_NODES;
    const uint2* H8b  = H8 + (size_t)br*N_NODES*16;
    const float* bvec = br ? bv1 : bv0;
    float*       hb   = hacc + (size_t)br*N_NODES*D_HID;

    int lane = threadIdx.x & 63;
    int wl   = threadIdx.x >> 6;
    int d = blockIdx.x*4 + wl;
    if (d >= N_NODES) return;
    int g  = lane >> 4;
    int fl = lane & 15;
    float aldd  = aldb[d];
    float eself = lrelu02(alsb[d] + aldd);
    float exs   = __builtin_amdgcn_exp2f(eself * LOG2E);
    // premultiplied self term (constant across hops)
    f32x2 self2[4];
    {
        uint2 hs = H8b[(size_t)d*16 + fl];
        f32x2 w2 = (f32x2){exs, exs};
        self2[0] = w2 * __builtin_amdgcn_cvt_pk_f32_fp8(hs.x, false);
        self2[1] = w2 * __builtin_amdgcn_cvt_pk_f32_fp8(hs.x, true);
        self2[2] = w2 * __builtin_amdgcn_cvt_pk_f32_fp8(hs.y, false);
        self2[3] = w2 * __builtin_amdgcn_cvt_pk_f32_fp8(hs.y, true);
    }
    f32x2 bv2[4];
    #pragma unroll
    for (int k=0;k<4;k++) bv2[k] = (f32x2){bvec[fl*8+2*k], bvec[fl*8+2*k+1]};
    f32x2 tot2[4];
    #pragma unroll
    for (int k=0;k<4;k++) tot2[k] = (f32x2){0.f, 0.f};

    for (int hop=0; hop<3; hop++){
        int s0 = offs[hop*N_NODES + d];
        int s1 = offs[hop*N_NODES + d + 1];
        int deg = s1 - s0;
        f32x2 acc2[4];
        #pragma unroll
        for (int k=0;k<4;k++) acc2[k] = (g==0) ? self2[k] : (f32x2){0.f,0.f};
        float es = 0.f;
        for (int base=0; base<deg; base+=64){
            int j = base + lane;
            int s = 0; float ex = 0.f;
            if (j < deg){
                s = esrc[s0 + j];
                ex = __builtin_amdgcn_exp2f(lrelu02(alsb[s] + aldd) * LOG2E);
            }
            es += ex;
            sh[wl][lane] = make_uint2((uint)s, __float_as_uint(ex));
            int cnt = min(64, deg - base);
            int i = g;
            for (; i + 4 < cnt; i += 8){
                uint2 seA = sh[wl][i];
                uint2 seB = sh[wl][i+4];
                uint2 hvA = H8b[(size_t)seA.x*16 + fl];
                uint2 hvB = H8b[(size_t)seB.x*16 + fl];
                float wA = __uint_as_float(seA.y);
                float wB = __uint_as_float(seB.y);
                fma8pk(hvA, (f32x2){wA,wA}, acc2);
                fma8pk(hvB, (f32x2){wB,wB}, acc2);
            }
            if (i < cnt){
                uint2 se = sh[wl][i];
                uint2 hv = H8b[(size_t)se.x*16 + fl];
                float w = __uint_as_float(se.y);
                fma8pk(hv, (f32x2){w,w}, acc2);
            }
        }
        for (int o=32;o;o>>=1) es += __shfl_xor(es,o);
        #pragma unroll
        for (int k=0;k<4;k++){
            float x0 = acc2[k][0], x1 = acc2[k][1];
            x0 += __shfl_xor(x0, 16); x0 += __shfl_xor(x0, 32);
            x1 += __shfl_xor(x1, 16); x1 += __shfl_xor(x1, 32);
            acc2[k][0] = x0; acc2[k][1] = x1;
        }
        float inv = 1.f / (es + exs);
        #pragma unroll
        for (int k=0;k<4;k++){
            tot2[k][0] += lrelu01(acc2[k][0]*inv + bv2[k][0]);
            tot2[k][1] += lrelu01(acc2[k][1]*inv + bv2[k][1]);
        }
    }
    if (g == 0){
        float4 w0 = make_float4(tot2[0][0],tot2[0][1],tot2[1][0],tot2[1][1]);
        float4 w1 = make_float4(tot2[2][0],tot2[2][1],tot2[3][0],tot2[3][1]);
        *reinterpret_cast<float4*>(hb + (size_t)d*D_HID + fl*8)     = w0;
        *reinterpret_cast<float4*>(hb + (size_t)d*D_HID + fl*8 + 4) = w1;
    }
}

// ---------- mean-pool per graph + branch FC (both branches) ----------
__global__ __launch_bounds__(256) void k_pool_fc(const float* __restrict__ hacc,
                    const int* __restrict__ b0, const int* __restrict__ b1,
                    const float* __restrict__ pW0, const float* __restrict__ pb0,
                    const float* __restrict__ pW1, const float* __restrict__ pb1,
                    float* __restrict__ xb){
    __shared__ float sums[2][128];
    __shared__ float pl[128];
    int br = blockIdx.y;
    const float* hb   = hacc + (size_t)br*N_NODES*D_HID;
    const int*   batch= br ? b1 : b0;
    const float* fcW  = br ? pW1 : pW0;
    const float* fcb  = br ? pb1 : pb0;
    int g = blockIdx.x;
    int t = threadIdx.x;
    int lo=0, hi=N_NODES;
    while (lo<hi){ int mid=(lo+hi)>>1; if (batch[mid] < g) lo=mid+1; else hi=mid; }
    int s = lo;
    lo = s; hi = N_NODES;
    while (lo<hi){ int mid=(lo+hi)>>1; if (batch[mid] < g+1) lo=mid+1; else hi=mid; }
    int e = lo;
    int f = t & 127, half = t >> 7;
    float sum = 0.f;
    for (int n=s+half; n<e; n+=2) sum += hb[(size_t)n*D_HID + f];
    sums[half][f] = sum;
    __syncthreads();
    if (t < 128){
        float cnt = (float)(e - s);
        pl[t] = (sums[0][t] + sums[1][t]) / fmaxf(cnt, 1.0f);
    }
    __syncthreads();
    if (t < 128){
        float a = fcb[t];
        for (int k=0;k<128;k++) a += pl[k]*fcW[k*128 + t];
        xb[(br*N_GRAPH + g)*128 + t] = lrelu01(a);
    }
}

// ---------- final MLP ----------
__global__ __launch_bounds__(256) void k_final(const float* __restrict__ xb,
                      const float* __restrict__ fc1W, const float* __restrict__ fc1b,
                      const float* __restrict__ fc2W, const float* __restrict__ fc2b,
                      const float* __restrict__ outW, const float* __restrict__ outb,
                      float* __restrict__ out){
    __shared__ float xc[256], y1[256], y2[64];
    int g = blockIdx.x, t = threadIdx.x;
    xc[t] = (t < 128) ? xb[g*128 + t] : xb[(N_GRAPH + g)*128 + (t-128)];
    __syncthreads();
    float a = fc1b[t];
    for (int k=0;k<256;k++) a += xc[k]*fc1W[k*256 + t];
    y1[t] = lrelu01(a);
    __syncthreads();
    if (t < 64){
        float a2 = fc2b[t];
        for (int k=0;k<256;k++) a2 += y1[k]*fc2W[k*64 + t];
        y2[t] = lrelu01(a2);
    }
    __syncthreads();
    if (t == 0){
        float z = outb[0];
        for (int k=0;k<64;k++) z += y2[k]*outW[k];
        out[g] = 1.f/(1.f + expf(-z));
    }
}

extern "C" void kernel_launch(void* const* d_in, const int* in_sizes, int n_in,
                              void* d_out, int out_size, void* d_ws, size_t ws_size,
                              hipStream_t stream){
    const float* X0 = (const float*)d_in[0];
    const float* X1 = (const float*)d_in[5];
    const int *e10=(const int*)d_in[1], *e20=(const int*)d_in[2], *e30=(const int*)d_in[3];
    const int *e11=(const int*)d_in[6], *e21=(const int*)d_in[7], *e31=(const int*)d_in[8];
    const int *b0=(const int*)d_in[4], *b1=(const int*)d_in[9];
    const float *W0=(const float*)d_in[10], *W1=(const float*)d_in[16];
    const float *as0=(const float*)d_in[11], *ad0=(const float*)d_in[12];
    const float *as1=(const float*)d_in[17], *ad1=(const float*)d_in[18];
    const float *bv0=(const float*)d_in[13], *bv1=(const float*)d_in[19];
    const float *pW0=(const float*)d_in[14], *pb0=(const float*)d_in[15];
    const float *pW1=(const float*)d_in[20], *pb1=(const float*)d_in[21];
    const float *fc1W=(const float*)d_in[22], *fc1b=(const float*)d_in[23];
    const float *fc2W=(const float*)d_in[24], *fc2b=(const float*)d_in[25];
    const float *outW=(const float*)d_in[26], *outb=(const float*)d_in[27];
    float* out = (float*)d_out;

    char* ws = (char*)d_ws;
    size_t o = 0;
    auto alloc = [&](size_t bytes)->char*{ char* p = ws + o; o += (bytes + 511) & ~(size_t)511; return p; };
    unsigned char* H8 = (unsigned char*)alloc((size_t)2*N_NODES*D_HID);
    float*  hacc  = (float*) alloc((size_t)2*N_NODES*D_HID*4);
    float*  als   = (float*) alloc((size_t)2*N_NODES*4);
    float*  ald   = (float*) alloc((size_t)2*N_NODES*4);
    int*    offs3 = (int*)   alloc((size_t)2*(NT3+1)*4);
    int*    esrc3 = (int*)   alloc((size_t)2*3*N_EDGES*4);
    int*    gcur  = (int*)   alloc((size_t)2*NB*4);
    uint*   pairs = (uint*)  alloc((size_t)2*NB*CAP*4);
    ushort* Wt    = (ushort*)alloc((size_t)2*D_HID*F_IN*2);
    float*  xb    = (float*) alloc((size_t)2*N_GRAPH*D_HID*4);

    k_prep    <<<1025, 256, 0, stream>>>(W0, W1, Wt, gcur);
    k_gemm    <<<dim3((N_NODES+BM-1)/BM, 2), 256, 0, stream>>>(X0, X1, Wt, as0, ad0, as1, ad1, H8, als, ald);
    k_bin     <<<2*NBIN_PB, 256, 0, stream>>>(e10, e20, e30, e11, e21, e31, gcur, pairs);
    k_localcsr<<<2*NB, 256, 0, stream>>>(gcur, pairs, offs3, esrc3);
    k_gat3    <<<dim3((N_NODES+3)/4, 2), 256, 0, stream>>>(offs3, esrc3, als, ald, (const uint2*)H8, bv0, bv1, hacc);
    k_pool_fc <<<dim3(N_GRAPH, 2), 256, 0, stream>>>(hacc, b0, b1, pW0, pb0, pW1, pb1, xb);
    k_final   <<<N_GRAPH, 256, 0, stream>>>(xb, fc1W, fc1b, fc2W, fc2b, outW, outb, out);
}

// Round 17
// 432.205 us; speedup vs baseline: 1.0095x; 1.0095x over previous
//
#include <hip/hip_runtime.h>
#include <hip/hip_bf16.h>
#include <math.h>

#define N_NODES 50000
#define N_EDGES 800000
#define N_GRAPH 128
#define F_IN    1024
#define D_HID   128
#define NT3     (3*N_NODES)
#define LOG2E   1.44269504f

// bucketed CSR build
#define NPB_SH  9
#define NPB     512
#define NB      ((NT3 + NPB - 1) / NPB)   // 293
#define CAP     10240
#define EPB     4096
#define NBIN_PB ((3*N_EDGES + EPB - 1) / EPB)   // 586 blocks per branch

typedef __bf16 bf16x8 __attribute__((ext_vector_type(8)));
typedef float  f32x4  __attribute__((ext_vector_type(4)));
typedef float  f32x2  __attribute__((ext_vector_type(2)));

__device__ __forceinline__ float lrelu01(float x){ return x > 0.f ? x : 0.01f*x; }
__device__ __forceinline__ float lrelu02(float x){ return x > 0.f ? x : 0.2f*x; }
__device__ __forceinline__ ushort f2bf(float v){
    __hip_bfloat16 hb = __float2bfloat16(v);
    return *reinterpret_cast<ushort*>(&hb);
}
__device__ __forceinline__ unsigned char f2fp8(float v){
    return (unsigned char)(__builtin_amdgcn_cvt_pk_fp8_f32(v, v, 0, false) & 0xFF);
}
// acc2[0..3] += w2 * fp8x8 (one uint2), packed f32x2 math
__device__ __forceinline__ void fma8pk(uint2 u, f32x2 w2, f32x2* acc2){
    acc2[0] += w2 * __builtin_amdgcn_cvt_pk_f32_fp8(u.x, false);
    acc2[1] += w2 * __builtin_amdgcn_cvt_pk_f32_fp8(u.x, true);
    acc2[2] += w2 * __builtin_amdgcn_cvt_pk_f32_fp8(u.y, false);
    acc2[3] += w2 * __builtin_amdgcn_cvt_pk_f32_fp8(u.y, true);
}

// ---------- prep: cast both W's to Wt[2][128][1024] bf16 + zero gcur ----------
__global__ void k_prep(const float* __restrict__ W0, const float* __restrict__ W1,
                       ushort* __restrict__ Wt, int* __restrict__ gcur){
    int b = blockIdx.x, t = threadIdx.x;
    if (b < 1024){
        int idx = b*256 + t;              // 0 .. 262143
        int br  = idx >> 17;              // 131072 per branch
        int r   = idx & 131071;
        int n = r >> 10, k = r & 1023;
        const float* W = br ? W1 : W0;
        Wt[idx] = f2bf(W[k*D_HID + n]);
    } else {
        for (int i=t; i<2*NB; i+=256) gcur[i] = 0;
    }
}

// ---------- GEMM both branches + fused al_s/al_d epilogue, fp8 H output ----------
#define BM  64
#define BK  64
#define LDP 72

__global__ __launch_bounds__(256) void k_gemm(const float* __restrict__ X0, const float* __restrict__ X1,
                                              const ushort* __restrict__ Wt,
                                              const float* __restrict__ as0, const float* __restrict__ ad0,
                                              const float* __restrict__ as1, const float* __restrict__ ad1,
                                              unsigned char* __restrict__ H8,
                                              float* __restrict__ als, float* __restrict__ ald){
    __shared__ ushort As[BM*LDP];
    __shared__ ushort Bs[D_HID*LDP];
    __shared__ float alp[4][2][64];
    int br = blockIdx.y;
    const float*  X   = br ? X1 : X0;
    const float*  asr = br ? as1 : as0;
    const float*  adr = br ? ad1 : ad0;
    const ushort* Wtb = Wt + (size_t)br*D_HID*F_IN;
    unsigned char* Hbb = H8 + (size_t)br*N_NODES*D_HID;

    int tid  = threadIdx.x;
    int m0   = blockIdx.x * BM;
    int lane = tid & 63;
    int wave = tid >> 6;
    int l15 = lane & 15, l4 = lane >> 4;
    int wcol = wave * 32;

    float4 pa[4];
    uint4  pb[4];

    auto loadA = [&](int kt){
        #pragma unroll
        for (int i=0;i<4;i++){
            int q = tid + i*256; int row = q >> 4; int kq = (q & 15) << 2;
            int gr = m0 + row;
            pa[i] = (gr < N_NODES) ? *reinterpret_cast<const float4*>(X + (size_t)gr*F_IN + kt + kq)
                                   : make_float4(0.f,0.f,0.f,0.f);
        }
    };
    auto loadB = [&](int kt){
        #pragma unroll
        for (int i=0;i<4;i++){
            int q = tid + i*256; int row = q >> 3; int ck = q & 7;
            pb[i] = *reinterpret_cast<const uint4*>(Wtb + row*F_IN + kt + ck*8);
        }
    };
    auto stage = [&](){
        #pragma unroll
        for (int i=0;i<4;i++){
            int q = tid + i*256; int row = q >> 4; int kq = (q & 15) << 2;
            ushort4 b; b.x=f2bf(pa[i].x); b.y=f2bf(pa[i].y); b.z=f2bf(pa[i].z); b.w=f2bf(pa[i].w);
            *reinterpret_cast<ushort4*>(&As[row*LDP + kq]) = b;
        }
        #pragma unroll
        for (int i=0;i<4;i++){
            int q = tid + i*256; int row = q >> 3; int ck = q & 7;
            *reinterpret_cast<uint2*>(&Bs[row*LDP + ck*8])     = make_uint2(pb[i].x, pb[i].y);
            *reinterpret_cast<uint2*>(&Bs[row*LDP + ck*8 + 4]) = make_uint2(pb[i].z, pb[i].w);
        }
    };

    f32x4 acc[4][2];
    #pragma unroll
    for (int i=0;i<4;i++) for (int j=0;j<2;j++) acc[i][j] = (f32x4){0.f,0.f,0.f,0.f};

    loadA(0); loadB(0);
    for (int kt = 0; kt < F_IN; kt += BK) {
        stage();
        __syncthreads();
        if (kt + BK < F_IN){ loadA(kt+BK); loadB(kt+BK); }
        #pragma unroll
        for (int kk = 0; kk < BK; kk += 32) {
            bf16x8 af[4], bfr[2];
            #pragma unroll
            for (int mi=0;mi<4;mi++)
                af[mi] = *reinterpret_cast<const bf16x8*>(&As[(mi*16+l15)*LDP + kk + l4*8]);
            #pragma unroll
            for (int ni=0;ni<2;ni++)
                bfr[ni] = *reinterpret_cast<const bf16x8*>(&Bs[(wcol+ni*16+l15)*LDP + kk + l4*8]);
            #pragma unroll
            for (int mi=0;mi<4;mi++)
                #pragma unroll
                for (int ni=0;ni<2;ni++)
                    acc[mi][ni] = __builtin_amdgcn_mfma_f32_16x16x32_bf16(af[mi], bfr[ni], acc[mi][ni], 0,0,0);
        }
        __syncthreads();
    }

    // epilogue: fp8 H write + fused al_s/al_d
    float asv[2], adv[2];
    #pragma unroll
    for (int ni=0;ni<2;ni++){
        int c = wcol + ni*16 + l15;
        asv[ni] = asr[c]; adv[ni] = adr[c];
    }
    #pragma unroll
    for (int mi=0;mi<4;mi++){
        #pragma unroll
        for (int jj=0;jj<4;jj++){
            int rrel = mi*16 + l4*4 + jj;
            int r = m0 + rrel;
            float ps = 0.f, pd = 0.f;
            #pragma unroll
            for (int ni=0;ni<2;ni++){
                float v = acc[mi][ni][jj];
                ps += v*asv[ni]; pd += v*adv[ni];
                if (r < N_NODES){
                    int c = wcol + ni*16 + l15;
                    Hbb[(size_t)r*D_HID + c] = f2fp8(v);
                }
            }
            #pragma unroll
            for (int o=1;o<16;o<<=1){ ps += __shfl_xor(ps,o); pd += __shfl_xor(pd,o); }
            if (l15 == 0){ alp[wave][0][rrel] = ps; alp[wave][1][rrel] = pd; }
        }
    }
    __syncthreads();
    if (tid < 64){
        int r = m0 + tid;
        if (r < N_NODES){
            float s_ = alp[0][0][tid]+alp[1][0][tid]+alp[2][0][tid]+alp[3][0][tid];
            float d_ = alp[0][1][tid]+alp[1][1][tid]+alp[2][1][tid]+alp[3][1][tid];
            als[br*N_NODES + r] = s_;
            ald[br*N_NODES + r] = d_;
        }
    }
}

// ---------- bucketed CSR: bin (both branches) ----------
__global__ __launch_bounds__(256) void k_bin(const int* __restrict__ e10, const int* __restrict__ e20,
                                             const int* __restrict__ e30,
                                             const int* __restrict__ e11, const int* __restrict__ e21,
                                             const int* __restrict__ e31,
                                             int* __restrict__ gcur, uint* __restrict__ pairs){
    __shared__ int hist[NB];
    __shared__ int start[NB];
    int blk = blockIdx.x;
    int br    = blk / NBIN_PB;
    int chunk = blk - br*NBIN_PB;
    int tid = threadIdx.x;
    for (int b=tid; b<NB; b+=256) hist[b]=0;
    __syncthreads();
    long base = (long)chunk * EPB;
    int  myb[16]; uint mypk[16];
    #pragma unroll
    for (int i=0;i<16;i++){
        long idx = base + i*256 + tid;
        int b = -1; uint pk = 0;
        if (idx < 3L*N_EDGES){
            int hop = (idx >= 2L*N_EDGES) ? 2 : (idx >= (long)N_EDGES) ? 1 : 0;
            int e   = (int)(idx - (long)hop*N_EDGES);
            const int* ei = (br==0) ? ((hop==0)?e10:(hop==1)?e20:e30)
                                    : ((hop==0)?e11:(hop==1)?e21:e31);
            int src = ei[e];
            int vd  = hop*N_NODES + ei[N_EDGES + e];
            b   = vd >> NPB_SH;
            pk  = (uint)src | ((uint)(vd & (NPB-1)) << 16);
            atomicAdd(&hist[b], 1);
        }
        myb[i]=b; mypk[i]=pk;
    }
    __syncthreads();
    for (int b=tid; b<NB; b+=256){
        int h = hist[b];
        start[b] = (h>0) ? atomicAdd(&gcur[br*NB + b], h) : 0;
    }
    __syncthreads();
    for (int b=tid; b<NB; b+=256) hist[b] = start[b];
    __syncthreads();
    #pragma unroll
    for (int i=0;i<16;i++){
        int b = myb[i];
        if (b >= 0){
            int pos = atomicAdd(&hist[b], 1);
            if (pos < CAP) pairs[((size_t)(br*NB + b))*CAP + pos] = mypk[i];
        }
    }
}

// ---------- localcsr: per-block inline bucket prefix + local scan/fill ----------
__global__ __launch_bounds__(256) void k_localcsr(const int* __restrict__ gcur,
                                                  const uint* __restrict__ pairs,
                                                  int* __restrict__ offs3, int* __restrict__ esrc){
    __shared__ int sc[512];
    __shared__ int deg[NPB];
    __shared__ int cur[NPB];
    __shared__ int ss[256];
    int gb = blockIdx.x;
    int br = gb / NB, bb = gb - br*NB;
    int t = threadIdx.x;
    sc[t]     = (t < NB)       ? min(gcur[br*NB + t], CAP) : 0;
    sc[t+256] = (t+256 < NB)   ? min(gcur[br*NB + t+256], CAP) : 0;
    __syncthreads();
    for (int o=1;o<512;o<<=1){
        int v0 = (t>=o)     ? sc[t-o]     : 0;
        int v1 = (t+256>=o) ? sc[t+256-o] : 0;
        __syncthreads();
        sc[t] += v0; sc[t+256] += v1;
        __syncthreads();
    }
    int base = (bb==0) ? 0 : sc[bb-1];
    int cnt  = sc[bb] - base;
    int* offsb = offs3 + (size_t)br*(NT3+1);
    if (bb == NB-1 && t == 0) offsb[NT3] = sc[NB-1];

    deg[t]=0; deg[t+256]=0;
    __syncthreads();
    const uint* pbuf = pairs + ((size_t)(br*NB + bb))*CAP;
    for (int i=t; i<cnt; i+=256) atomicAdd(&deg[pbuf[i] >> 16], 1);
    __syncthreads();
    int a0 = deg[2*t], a1 = deg[2*t+1];
    int ps = a0 + a1;
    ss[t] = ps; __syncthreads();
    for (int o=1;o<256;o<<=1){
        int u = (t>=o) ? ss[t-o] : 0;
        __syncthreads(); ss[t] += u; __syncthreads();
    }
    int ex = ss[t] - ps;
    __syncthreads();
    deg[2*t] = ex; deg[2*t+1] = ex + a0;
    cur[2*t] = ex; cur[2*t+1] = ex + a0;
    __syncthreads();
    int vd0 = bb << NPB_SH;
    for (int l=t; l<NPB; l+=256){
        int vd = vd0 + l;
        if (vd < NT3) offsb[vd] = base + deg[l];
    }
    int* esrcb = esrc + (size_t)br*3*N_EDGES;
    for (int i=t; i<cnt; i+=256){
        uint p = pbuf[i];
        int pos = atomicAdd(&cur[p >> 16], 1);
        esrcb[base + pos] = (int)(p & 0xFFFFu);
    }
}

// ---------- GAT aggregate: ONE BRANCH per dispatch (halved L2 working set) ----------
__global__ __launch_bounds__(256) void k_gat3(const int* __restrict__ offs3, const int* __restrict__ esrc3,
                     const float* __restrict__ als, const float* __restrict__ ald,
                     const uint2* __restrict__ H8,
                     const float* __restrict__ bv0, const float* __restrict__ bv1,
                     float* __restrict__ hacc, int br){
    __shared__ uint2 sh[4][64];
    const int*   offs = offs3 + (size_t)br*(NT3+1);
    const int*   esrc = esrc3 + (size_t)br*3*N_EDGES;
    const float* alsb = als + br*N_NODES;
    const float* aldb = ald + br*N_NODES;
    const uint2* H8b  = H8 + (size_t)br*N_NODES*16;
    const float* bvec = br ? bv1 : bv0;
    float*       hb   = hacc + (size_t)br*N_NODES*D_HID;

    int lane = threadIdx.x & 63;
    int wl   = threadIdx.x >> 6;
    int d = blockIdx.x*4 + wl;
    if (d >= N_NODES) return;
    int g  = lane >> 4;
    int fl = lane & 15;
    float aldd  = aldb[d];
    float eself = lrelu02(alsb[d] + aldd);
    float exs   = __builtin_amdgcn_exp2f(eself * LOG2E);
    // premultiplied self term (constant across hops)
    f32x2 self2[4];
    {
        uint2 hs = H8b[(size_t)d*16 + fl];
        f32x2 w2 = (f32x2){exs, exs};
        self2[0] = w2 * __builtin_amdgcn_cvt_pk_f32_fp8(hs.x, false);
        self2[1] = w2 * __builtin_amdgcn_cvt_pk_f32_fp8(hs.x, true);
        self2[2] = w2 * __builtin_amdgcn_cvt_pk_f32_fp8(hs.y, false);
        self2[3] = w2 * __builtin_amdgcn_cvt_pk_f32_fp8(hs.y, true);
    }
    f32x2 bv2[4];
    #pragma unroll
    for (int k=0;k<4;k++) bv2[k] = (f32x2){bvec[fl*8+2*k], bvec[fl*8+2*k+1]};
    f32x2 tot2[4];
    #pragma unroll
    for (int k=0;k<4;k++) tot2[k] = (f32x2){0.f, 0.f};

    for (int hop=0; hop<3; hop++){
        int s0 = offs[hop*N_NODES + d];
        int s1 = offs[hop*N_NODES + d + 1];
        int deg = s1 - s0;
        f32x2 acc2[4];
        #pragma unroll
        for (int k=0;k<4;k++) acc2[k] = (g==0) ? self2[k] : (f32x2){0.f,0.f};
        float es = 0.f;
        for (int base=0; base<deg; base+=64){
            int j = base + lane;
            int s = 0; float ex = 0.f;
            if (j < deg){
                s = esrc[s0 + j];
                ex = __builtin_amdgcn_exp2f(lrelu02(alsb[s] + aldd) * LOG2E);
            }
            es += ex;
            sh[wl][lane] = make_uint2((uint)s, __float_as_uint(ex));
            int cnt = min(64, deg - base);
            int i = g;
            for (; i + 4 < cnt; i += 8){
                uint2 seA = sh[wl][i];
                uint2 seB = sh[wl][i+4];
                uint2 hvA = H8b[(size_t)seA.x*16 + fl];
                uint2 hvB = H8b[(size_t)seB.x*16 + fl];
                float wA = __uint_as_float(seA.y);
                float wB = __uint_as_float(seB.y);
                fma8pk(hvA, (f32x2){wA,wA}, acc2);
                fma8pk(hvB, (f32x2){wB,wB}, acc2);
            }
            if (i < cnt){
                uint2 se = sh[wl][i];
                uint2 hv = H8b[(size_t)se.x*16 + fl];
                float w = __uint_as_float(se.y);
                fma8pk(hv, (f32x2){w,w}, acc2);
            }
        }
        for (int o=32;o;o>>=1) es += __shfl_xor(es,o);
        #pragma unroll
        for (int k=0;k<4;k++){
            float x0 = acc2[k][0], x1 = acc2[k][1];
            x0 += __shfl_xor(x0, 16); x0 += __shfl_xor(x0, 32);
            x1 += __shfl_xor(x1, 16); x1 += __shfl_xor(x1, 32);
            acc2[k][0] = x0; acc2[k][1] = x1;
        }
        float inv = 1.f / (es + exs);
        #pragma unroll
        for (int k=0;k<4;k++){
            tot2[k][0] += lrelu01(acc2[k][0]*inv + bv2[k][0]);
            tot2[k][1] += lrelu01(acc2[k][1]*inv + bv2[k][1]);
        }
    }
    if (g == 0){
        float4 w0 = make_float4(tot2[0][0],tot2[0][1],tot2[1][0],tot2[1][1]);
        float4 w1 = make_float4(tot2[2][0],tot2[2][1],tot2[3][0],tot2[3][1]);
        *reinterpret_cast<float4*>(hb + (size_t)d*D_HID + fl*8)     = w0;
        *reinterpret_cast<float4*>(hb + (size_t)d*D_HID + fl*8 + 4) = w1;
    }
}

// ---------- mean-pool per graph + branch FC (both branches) ----------
__global__ __launch_bounds__(256) void k_pool_fc(const float* __restrict__ hacc,
                    const int* __restrict__ b0, const int* __restrict__ b1,
                    const float* __restrict__ pW0, const float* __restrict__ pb0,
                    const float* __restrict__ pW1, const float* __restrict__ pb1,
                    float* __restrict__ xb){
    __shared__ float sums[2][128];
    __shared__ float pl[128];
    int br = blockIdx.y;
    const float* hb   = hacc + (size_t)br*N_NODES*D_HID;
    const int*   batch= br ? b1 : b0;
    const float* fcW  = br ? pW1 : pW0;
    const float* fcb  = br ? pb1 : pb0;
    int g = blockIdx.x;
    int t = threadIdx.x;
    int lo=0, hi=N_NODES;
    while (lo<hi){ int mid=(lo+hi)>>1; if (batch[mid] < g) lo=mid+1; else hi=mid; }
    int s = lo;
    lo = s; hi = N_NODES;
    while (lo<hi){ int mid=(lo+hi)>>1; if (batch[mid] < g+1) lo=mid+1; else hi=mid; }
    int e = lo;
    int f = t & 127, half = t >> 7;
    float sum = 0.f;
    for (int n=s+half; n<e; n+=2) sum += hb[(size_t)n*D_HID + f];
    sums[half][f] = sum;
    __syncthreads();
    if (t < 128){
        float cnt = (float)(e - s);
        pl[t] = (sums[0][t] + sums[1][t]) / fmaxf(cnt, 1.0f);
    }
    __syncthreads();
    if (t < 128){
        float a = fcb[t];
        for (int k=0;k<128;k++) a += pl[k]*fcW[k*128 + t];
        xb[(br*N_GRAPH + g)*128 + t] = lrelu01(a);
    }
}

// ---------- final MLP ----------
__global__ __launch_bounds__(256) void k_final(const float* __restrict__ xb,
                      const float* __restrict__ fc1W, const float* __restrict__ fc1b,
                      const float* __restrict__ fc2W, const float* __restrict__ fc2b,
                      const float* __restrict__ outW, const float* __restrict__ outb,
                      float* __restrict__ out){
    __shared__ float xc[256], y1[256], y2[64];
    int g = blockIdx.x, t = threadIdx.x;
    xc[t] = (t < 128) ? xb[g*128 + t] : xb[(N_GRAPH + g)*128 + (t-128)];
    __syncthreads();
    float a = fc1b[t];
    for (int k=0;k<256;k++) a += xc[k]*fc1W[k*256 + t];
    y1[t] = lrelu01(a);
    __syncthreads();
    if (t < 64){
        float a2 = fc2b[t];
        for (int k=0;k<256;k++) a2 += y1[k]*fc2W[k*64 + t];
        y2[t] = lrelu01(a2);
    }
    __syncthreads();
    if (t == 0){
        float z = outb[0];
        for (int k=0;k<64;k++) z += y2[k]*outW[k];
        out[g] = 1.f/(1.f + expf(-z));
    }
}

extern "C" void kernel_launch(void* const* d_in, const int* in_sizes, int n_in,
                              void* d_out, int out_size, void* d_ws, size_t ws_size,
                              hipStream_t stream){
    const float* X0 = (const float*)d_in[0];
    const float* X1 = (const float*)d_in[5];
    const int *e10=(const int*)d_in[1], *e20=(const int*)d_in[2], *e30=(const int*)d_in[3];
    const int *e11=(const int*)d_in[6], *e21=(const int*)d_in[7], *e31=(const int*)d_in[8];
    const int *b0=(const int*)d_in[4], *b1=(const int*)d_in[9];
    const float *W0=(const float*)d_in[10], *W1=(const float*)d_in[16];
    const float *as0=(const float*)d_in[11], *ad0=(const float*)d_in[12];
    const float *as1=(const float*)d_in[17], *ad1=(const float*)d_in[18];
    const float *bv0=(const float*)d_in[13], *bv1=(const float*)d_in[19];
    const float *pW0=(const float*)d_in[14], *pb0=(const float*)d_in[15];
    const float *pW1=(const float*)d_in[20], *pb1=(const float*)d_in[21];
    const float *fc1W=(const float*)d_in[22], *fc1b=(const float*)d_in[23];
    const float *fc2W=(const float*)d_in[24], *fc2b=(const float*)d_in[25];
    const float *outW=(const float*)d_in[26], *outb=(const float*)d_in[27];
    float* out = (float*)d_out;

    char* ws = (char*)d_ws;
    size_t o = 0;
    auto alloc = [&](size_t bytes)->char*{ char* p = ws + o; o += (bytes + 511) & ~(size_t)511; return p; };
    unsigned char* H8 = (unsigned char*)alloc((size_t)2*N_NODES*D_HID);
    float*  hacc  = (float*) alloc((size_t)2*N_NODES*D_HID*4);
    float*  als   = (float*) alloc((size_t)2*N_NODES*4);
    float*  ald   = (float*) alloc((size_t)2*N_NODES*4);
    int*    offs3 = (int*)   alloc((size_t)2*(NT3+1)*4);
    int*    esrc3 = (int*)   alloc((size_t)2*3*N_EDGES*4);
    int*    gcur  = (int*)   alloc((size_t)2*NB*4);
    uint*   pairs = (uint*)  alloc((size_t)2*NB*CAP*4);
    ushort* Wt    = (ushort*)alloc((size_t)2*D_HID*F_IN*2);
    float*  xb    = (float*) alloc((size_t)2*N_GRAPH*D_HID*4);

    k_prep    <<<1025, 256, 0, stream>>>(W0, W1, Wt, gcur);
    k_gemm    <<<dim3((N_NODES+BM-1)/BM, 2), 256, 0, stream>>>(X0, X1, Wt, as0, ad0, as1, ad1, H8, als, ald);
    k_bin     <<<2*NBIN_PB, 256, 0, stream>>>(e10, e20, e30, e11, e21, e31, gcur, pairs);
    k_localcsr<<<2*NB, 256, 0, stream>>>(gcur, pairs, offs3, esrc3);
    k_gat3    <<<(N_NODES+3)/4, 256, 0, stream>>>(offs3, esrc3, als, ald, (const uint2*)H8, bv0, bv1, hacc, 0);
    k_gat3    <<<(N_NODES+3)/4, 256, 0, stream>>>(offs3, esrc3, als, ald, (const uint2*)H8, bv0, bv1, hacc, 1);
    k_pool_fc <<<dim3(N_GRAPH, 2), 256, 0, stream>>>(hacc, b0, b1, pW0, pb0, pW1, pb1, xb);
    k_final   <<<N_GRAPH, 256, 0, stream>>>(xb, fc1W, fc1b, fc2W, fc2b, outW, outb, out);
}

// Round 18
// 422.902 us; speedup vs baseline: 1.0317x; 1.0220x over previous
//
#include <hip/hip_runtime.h>
#include <hip/hip_bf16.h>
#include <math.h>

#define N_NODES 50000
#define N_EDGES 800000
#define N_GRAPH 128
#define F_IN    1024
#define D_HID   128
#define NT3     (3*N_NODES)
#define LOG2E   1.44269504f

// bucketed CSR build
#define NPB_SH  9
#define NPB     512
#define NB      ((NT3 + NPB - 1) / NPB)   // 293
#define CAP     10240
#define EPB     4096
#define NBIN_PB ((3*N_EDGES + EPB - 1) / EPB)   // 586 blocks per branch

typedef __bf16 bf16x8 __attribute__((ext_vector_type(8)));
typedef float  f32x4  __attribute__((ext_vector_type(4)));
typedef float  f32x2  __attribute__((ext_vector_type(2)));

__device__ __forceinline__ float lrelu01(float x){ return x > 0.f ? x : 0.01f*x; }
__device__ __forceinline__ float lrelu02(float x){ return x > 0.f ? x : 0.2f*x; }
__device__ __forceinline__ ushort f2bf(float v){
    __hip_bfloat16 hb = __float2bfloat16(v);
    return *reinterpret_cast<ushort*>(&hb);
}
__device__ __forceinline__ unsigned char f2fp8(float v){
    return (unsigned char)(__builtin_amdgcn_cvt_pk_fp8_f32(v, v, 0, false) & 0xFF);
}
// acc2[0..3] += w2 * fp8x8 (one uint2), packed f32x2 math
__device__ __forceinline__ void fma8pk(uint2 u, f32x2 w2, f32x2* acc2){
    acc2[0] += w2 * __builtin_amdgcn_cvt_pk_f32_fp8(u.x, false);
    acc2[1] += w2 * __builtin_amdgcn_cvt_pk_f32_fp8(u.x, true);
    acc2[2] += w2 * __builtin_amdgcn_cvt_pk_f32_fp8(u.y, false);
    acc2[3] += w2 * __builtin_amdgcn_cvt_pk_f32_fp8(u.y, true);
}

// ---------- prep: cast both W's to Wt[2][128][1024] bf16 + zero gcur ----------
__global__ void k_prep(const float* __restrict__ W0, const float* __restrict__ W1,
                       ushort* __restrict__ Wt, int* __restrict__ gcur){
    int b = blockIdx.x, t = threadIdx.x;
    if (b < 1024){
        int idx = b*256 + t;              // 0 .. 262143
        int br  = idx >> 17;              // 131072 per branch
        int r   = idx & 131071;
        int n = r >> 10, k = r & 1023;
        const float* W = br ? W1 : W0;
        Wt[idx] = f2bf(W[k*D_HID + n]);
    } else {
        for (int i=t; i<2*NB; i+=256) gcur[i] = 0;
    }
}

// ---------- GEMM both branches + fused al_s/al_d epilogue, fp8 H output ----------
#define BM  64
#define BK  64
#define LDP 72

__global__ __launch_bounds__(256) void k_gemm(const float* __restrict__ X0, const float* __restrict__ X1,
                                              const ushort* __restrict__ Wt,
                                              const float* __restrict__ as0, const float* __restrict__ ad0,
                                              const float* __restrict__ as1, const float* __restrict__ ad1,
                                              unsigned char* __restrict__ H8,
                                              float* __restrict__ als, float* __restrict__ ald){
    __shared__ ushort As[BM*LDP];
    __shared__ ushort Bs[D_HID*LDP];
    __shared__ float alp[4][2][64];
    int br = blockIdx.y;
    const float*  X   = br ? X1 : X0;
    const float*  asr = br ? as1 : as0;
    const float*  adr = br ? ad1 : ad0;
    const ushort* Wtb = Wt + (size_t)br*D_HID*F_IN;
    unsigned char* Hbb = H8 + (size_t)br*N_NODES*D_HID;

    int tid  = threadIdx.x;
    int m0   = blockIdx.x * BM;
    int lane = tid & 63;
    int wave = tid >> 6;
    int l15 = lane & 15, l4 = lane >> 4;
    int wcol = wave * 32;

    float4 pa[4];
    uint4  pb[4];

    auto loadA = [&](int kt){
        #pragma unroll
        for (int i=0;i<4;i++){
            int q = tid + i*256; int row = q >> 4; int kq = (q & 15) << 2;
            int gr = m0 + row;
            pa[i] = (gr < N_NODES) ? *reinterpret_cast<const float4*>(X + (size_t)gr*F_IN + kt + kq)
                                   : make_float4(0.f,0.f,0.f,0.f);
        }
    };
    auto loadB = [&](int kt){
        #pragma unroll
        for (int i=0;i<4;i++){
            int q = tid + i*256; int row = q >> 3; int ck = q & 7;
            pb[i] = *reinterpret_cast<const uint4*>(Wtb + row*F_IN + kt + ck*8);
        }
    };
    auto stage = [&](){
        #pragma unroll
        for (int i=0;i<4;i++){
            int q = tid + i*256; int row = q >> 4; int kq = (q & 15) << 2;
            ushort4 b; b.x=f2bf(pa[i].x); b.y=f2bf(pa[i].y); b.z=f2bf(pa[i].z); b.w=f2bf(pa[i].w);
            *reinterpret_cast<ushort4*>(&As[row*LDP + kq]) = b;
        }
        #pragma unroll
        for (int i=0;i<4;i++){
            int q = tid + i*256; int row = q >> 3; int ck = q & 7;
            *reinterpret_cast<uint2*>(&Bs[row*LDP + ck*8])     = make_uint2(pb[i].x, pb[i].y);
            *reinterpret_cast<uint2*>(&Bs[row*LDP + ck*8 + 4]) = make_uint2(pb[i].z, pb[i].w);
        }
    };

    f32x4 acc[4][2];
    #pragma unroll
    for (int i=0;i<4;i++) for (int j=0;j<2;j++) acc[i][j] = (f32x4){0.f,0.f,0.f,0.f};

    loadA(0); loadB(0);
    for (int kt = 0; kt < F_IN; kt += BK) {
        stage();
        __syncthreads();
        if (kt + BK < F_IN){ loadA(kt+BK); loadB(kt+BK); }
        #pragma unroll
        for (int kk = 0; kk < BK; kk += 32) {
            bf16x8 af[4], bfr[2];
            #pragma unroll
            for (int mi=0;mi<4;mi++)
                af[mi] = *reinterpret_cast<const bf16x8*>(&As[(mi*16+l15)*LDP + kk + l4*8]);
            #pragma unroll
            for (int ni=0;ni<2;ni++)
                bfr[ni] = *reinterpret_cast<const bf16x8*>(&Bs[(wcol+ni*16+l15)*LDP + kk + l4*8]);
            #pragma unroll
            for (int mi=0;mi<4;mi++)
                #pragma unroll
                for (int ni=0;ni<2;ni++)
                    acc[mi][ni] = __builtin_amdgcn_mfma_f32_16x16x32_bf16(af[mi], bfr[ni], acc[mi][ni], 0,0,0);
        }
        __syncthreads();
    }

    // epilogue: fp8 H write + fused al_s/al_d
    float asv[2], adv[2];
    #pragma unroll
    for (int ni=0;ni<2;ni++){
        int c = wcol + ni*16 + l15;
        asv[ni] = asr[c]; adv[ni] = adr[c];
    }
    #pragma unroll
    for (int mi=0;mi<4;mi++){
        #pragma unroll
        for (int jj=0;jj<4;jj++){
            int rrel = mi*16 + l4*4 + jj;
            int r = m0 + rrel;
            float ps = 0.f, pd = 0.f;
            #pragma unroll
            for (int ni=0;ni<2;ni++){
                float v = acc[mi][ni][jj];
                ps += v*asv[ni]; pd += v*adv[ni];
                if (r < N_NODES){
                    int c = wcol + ni*16 + l15;
                    Hbb[(size_t)r*D_HID + c] = f2fp8(v);
                }
            }
            #pragma unroll
            for (int o=1;o<16;o<<=1){ ps += __shfl_xor(ps,o); pd += __shfl_xor(pd,o); }
            if (l15 == 0){ alp[wave][0][rrel] = ps; alp[wave][1][rrel] = pd; }
        }
    }
    __syncthreads();
    if (tid < 64){
        int r = m0 + tid;
        if (r < N_NODES){
            float s_ = alp[0][0][tid]+alp[1][0][tid]+alp[2][0][tid]+alp[3][0][tid];
            float d_ = alp[0][1][tid]+alp[1][1][tid]+alp[2][1][tid]+alp[3][1][tid];
            als[br*N_NODES + r] = s_;
            ald[br*N_NODES + r] = d_;
        }
    }
}

// ---------- bucketed CSR: bin (both branches) ----------
__global__ __launch_bounds__(256) void k_bin(const int* __restrict__ e10, const int* __restrict__ e20,
                                             const int* __restrict__ e30,
                                             const int* __restrict__ e11, const int* __restrict__ e21,
                                             const int* __restrict__ e31,
                                             int* __restrict__ gcur, uint* __restrict__ pairs){
    __shared__ int hist[NB];
    __shared__ int start[NB];
    int blk = blockIdx.x;
    int br    = blk / NBIN_PB;
    int chunk = blk - br*NBIN_PB;
    int tid = threadIdx.x;
    for (int b=tid; b<NB; b+=256) hist[b]=0;
    __syncthreads();
    long base = (long)chunk * EPB;
    int  myb[16]; uint mypk[16];
    #pragma unroll
    for (int i=0;i<16;i++){
        long idx = base + i*256 + tid;
        int b = -1; uint pk = 0;
        if (idx < 3L*N_EDGES){
            int hop = (idx >= 2L*N_EDGES) ? 2 : (idx >= (long)N_EDGES) ? 1 : 0;
            int e   = (int)(idx - (long)hop*N_EDGES);
            const int* ei = (br==0) ? ((hop==0)?e10:(hop==1)?e20:e30)
                                    : ((hop==0)?e11:(hop==1)?e21:e31);
            int src = ei[e];
            int vd  = hop*N_NODES + ei[N_EDGES + e];
            b   = vd >> NPB_SH;
            pk  = (uint)src | ((uint)(vd & (NPB-1)) << 16);
            atomicAdd(&hist[b], 1);
        }
        myb[i]=b; mypk[i]=pk;
    }
    __syncthreads();
    for (int b=tid; b<NB; b+=256){
        int h = hist[b];
        start[b] = (h>0) ? atomicAdd(&gcur[br*NB + b], h) : 0;
    }
    __syncthreads();
    for (int b=tid; b<NB; b+=256) hist[b] = start[b];
    __syncthreads();
    #pragma unroll
    for (int i=0;i<16;i++){
        int b = myb[i];
        if (b >= 0){
            int pos = atomicAdd(&hist[b], 1);
            if (pos < CAP) pairs[((size_t)(br*NB + b))*CAP + pos] = mypk[i];
        }
    }
}

// ---------- localcsr: per-block inline bucket prefix + local scan/fill ----------
__global__ __launch_bounds__(256) void k_localcsr(const int* __restrict__ gcur,
                                                  const uint* __restrict__ pairs,
                                                  int* __restrict__ offs3, int* __restrict__ esrc){
    __shared__ int sc[512];
    __shared__ int deg[NPB];
    __shared__ int cur[NPB];
    __shared__ int ss[256];
    int gb = blockIdx.x;
    int br = gb / NB, bb = gb - br*NB;
    int t = threadIdx.x;
    sc[t]     = (t < NB)       ? min(gcur[br*NB + t], CAP) : 0;
    sc[t+256] = (t+256 < NB)   ? min(gcur[br*NB + t+256], CAP) : 0;
    __syncthreads();
    for (int o=1;o<512;o<<=1){
        int v0 = (t>=o)     ? sc[t-o]     : 0;
        int v1 = (t+256>=o) ? sc[t+256-o] : 0;
        __syncthreads();
        sc[t] += v0; sc[t+256] += v1;
        __syncthreads();
    }
    int base = (bb==0) ? 0 : sc[bb-1];
    int cnt  = sc[bb] - base;
    int* offsb = offs3 + (size_t)br*(NT3+1);
    if (bb == NB-1 && t == 0) offsb[NT3] = sc[NB-1];

    deg[t]=0; deg[t+256]=0;
    __syncthreads();
    const uint* pbuf = pairs + ((size_t)(br*NB + bb))*CAP;
    for (int i=t; i<cnt; i+=256) atomicAdd(&deg[pbuf[i] >> 16], 1);
    __syncthreads();
    int a0 = deg[2*t], a1 = deg[2*t+1];
    int ps = a0 + a1;
    ss[t] = ps; __syncthreads();
    for (int o=1;o<256;o<<=1){
        int u = (t>=o) ? ss[t-o] : 0;
        __syncthreads(); ss[t] += u; __syncthreads();
    }
    int ex = ss[t] - ps;
    __syncthreads();
    deg[2*t] = ex; deg[2*t+1] = ex + a0;
    cur[2*t] = ex; cur[2*t+1] = ex + a0;
    __syncthreads();
    int vd0 = bb << NPB_SH;
    for (int l=t; l<NPB; l+=256){
        int vd = vd0 + l;
        if (vd < NT3) offsb[vd] = base + deg[l];
    }
    int* esrcb = esrc + (size_t)br*3*N_EDGES;
    for (int i=t; i<cnt; i+=256){
        uint p = pbuf[i];
        int pos = atomicAdd(&cur[p >> 16], 1);
        esrcb[base + pos] = (int)(p & 0xFFFFu);
    }
}

// ---------- GAT aggregate: fp8 rows, 4x16-lane groups, unroll-2, pk-FMA ----------
__global__ __launch_bounds__(256) void k_gat3(const int* __restrict__ offs3, const int* __restrict__ esrc3,
                     const float* __restrict__ als, const float* __restrict__ ald,
                     const uint2* __restrict__ H8,
                     const float* __restrict__ bv0, const float* __restrict__ bv1,
                     float* __restrict__ hacc){
    __shared__ uint2 sh[4][64];
    int br = blockIdx.y;
    const int*   offs = offs3 + (size_t)br*(NT3+1);
    const int*   esrc = esrc3 + (size_t)br*3*N_EDGES;
    const float* alsb = als + br*N_NODES;
    const float* aldb = ald + br*N_NODES;
    const uint2* H8b  = H8 + (size_t)br*N_NODES*16;
    const float* bvec = br ? bv1 : bv0;
    float*       hb   = hacc + (size_t)br*N_NODES*D_HID;

    int lane = threadIdx.x & 63;
    int wl   = threadIdx.x >> 6;
    int d = blockIdx.x*4 + wl;
    if (d >= N_NODES) return;
    int g  = lane >> 4;
    int fl = lane & 15;
    float aldd  = aldb[d];
    float eself = lrelu02(alsb[d] + aldd);
    float exs   = __builtin_amdgcn_exp2f(eself * LOG2E);
    // premultiplied self term (constant across hops)
    f32x2 self2[4];
    {
        uint2 hs = H8b[(size_t)d*16 + fl];
        f32x2 w2 = (f32x2){exs, exs};
        self2[0] = w2 * __builtin_amdgcn_cvt_pk_f32_fp8(hs.x, false);
        self2[1] = w2 * __builtin_amdgcn_cvt_pk_f32_fp8(hs.x, true);
        self2[2] = w2 * __builtin_amdgcn_cvt_pk_f32_fp8(hs.y, false);
        self2[3] = w2 * __builtin_amdgcn_cvt_pk_f32_fp8(hs.y, true);
    }
    f32x2 bv2[4];
    #pragma unroll
    for (int k=0;k<4;k++) bv2[k] = (f32x2){bvec[fl*8+2*k], bvec[fl*8+2*k+1]};
    f32x2 tot2[4];
    #pragma unroll
    for (int k=0;k<4;k++) tot2[k] = (f32x2){0.f, 0.f};

    for (int hop=0; hop<3; hop++){
        int s0 = offs[hop*N_NODES + d];
        int s1 = offs[hop*N_NODES + d + 1];
        int deg = s1 - s0;
        f32x2 acc2[4];
        #pragma unroll
        for (int k=0;k<4;k++) acc2[k] = (g==0) ? self2[k] : (f32x2){0.f,0.f};
        float es = 0.f;
        for (int base=0; base<deg; base+=64){
            int j = base + lane;
            int s = 0; float ex = 0.f;
            if (j < deg){
                s = esrc[s0 + j];
                ex = __builtin_amdgcn_exp2f(lrelu02(alsb[s] + aldd) * LOG2E);
            }
            es += ex;
            sh[wl][lane] = make_uint2((uint)s, __float_as_uint(ex));
            int cnt = min(64, deg - base);
            int i = g;
            for (; i + 4 < cnt; i += 8){
                uint2 seA = sh[wl][i];
                uint2 seB = sh[wl][i+4];
                uint2 hvA = H8b[(size_t)seA.x*16 + fl];
                uint2 hvB = H8b[(size_t)seB.x*16 + fl];
                float wA = __uint_as_float(seA.y);
                float wB = __uint_as_float(seB.y);
                fma8pk(hvA, (f32x2){wA,wA}, acc2);
                fma8pk(hvB, (f32x2){wB,wB}, acc2);
            }
            if (i < cnt){
                uint2 se = sh[wl][i];
                uint2 hv = H8b[(size_t)se.x*16 + fl];
                float w = __uint_as_float(se.y);
                fma8pk(hv, (f32x2){w,w}, acc2);
            }
        }
        for (int o=32;o;o>>=1) es += __shfl_xor(es,o);
        #pragma unroll
        for (int k=0;k<4;k++){
            float x0 = acc2[k][0], x1 = acc2[k][1];
            x0 += __shfl_xor(x0, 16); x0 += __shfl_xor(x0, 32);
            x1 += __shfl_xor(x1, 16); x1 += __shfl_xor(x1, 32);
            acc2[k][0] = x0; acc2[k][1] = x1;
        }
        float inv = 1.f / (es + exs);
        #pragma unroll
        for (int k=0;k<4;k++){
            tot2[k][0] += lrelu01(acc2[k][0]*inv + bv2[k][0]);
            tot2[k][1] += lrelu01(acc2[k][1]*inv + bv2[k][1]);
        }
    }
    if (g == 0){
        float4 w0 = make_float4(tot2[0][0],tot2[0][1],tot2[1][0],tot2[1][1]);
        float4 w1 = make_float4(tot2[2][0],tot2[2][1],tot2[3][0],tot2[3][1]);
        *reinterpret_cast<float4*>(hb + (size_t)d*D_HID + fl*8)     = w0;
        *reinterpret_cast<float4*>(hb + (size_t)d*D_HID + fl*8 + 4) = w1;
    }
}

// ---------- mean-pool per graph + branch FC (both branches) ----------
__global__ __launch_bounds__(256) void k_pool_fc(const float* __restrict__ hacc,
                    const int* __restrict__ b0, const int* __restrict__ b1,
                    const float* __restrict__ pW0, const float* __restrict__ pb0,
                    const float* __restrict__ pW1, const float* __restrict__ pb1,
                    float* __restrict__ xb){
    __shared__ float sums[2][128];
    __shared__ float pl[128];
    int br = blockIdx.y;
    const float* hb   = hacc + (size_t)br*N_NODES*D_HID;
    const int*   batch= br ? b1 : b0;
    const float* fcW  = br ? pW1 : pW0;
    const float* fcb  = br ? pb1 : pb0;
    int g = blockIdx.x;
    int t = threadIdx.x;
    int lo=0, hi=N_NODES;
    while (lo<hi){ int mid=(lo+hi)>>1; if (batch[mid] < g) lo=mid+1; else hi=mid; }
    int s = lo;
    lo = s; hi = N_NODES;
    while (lo<hi){ int mid=(lo+hi)>>1; if (batch[mid] < g+1) lo=mid+1; else hi=mid; }
    int e = lo;
    int f = t & 127, half = t >> 7;
    float sum = 0.f;
    for (int n=s+half; n<e; n+=2) sum += hb[(size_t)n*D_HID + f];
    sums[half][f] = sum;
    __syncthreads();
    if (t < 128){
        float cnt = (float)(e - s);
        pl[t] = (sums[0][t] + sums[1][t]) / fmaxf(cnt, 1.0f);
    }
    __syncthreads();
    if (t < 128){
        float a = fcb[t];
        for (int k=0;k<128;k++) a += pl[k]*fcW[k*128 + t];
        xb[(br*N_GRAPH + g)*128 + t] = lrelu01(a);
    }
}

// ---------- final MLP ----------
__global__ __launch_bounds__(256) void k_final(const float* __restrict__ xb,
                      const float* __restrict__ fc1W, const float* __restrict__ fc1b,
                      const float* __restrict__ fc2W, const float* __restrict__ fc2b,
                      const float* __restrict__ outW, const float* __restrict__ outb,
                      float* __restrict__ out){
    __shared__ float xc[256], y1[256], y2[64];
    int g = blockIdx.x, t = threadIdx.x;
    xc[t] = (t < 128) ? xb[g*128 + t] : xb[(N_GRAPH + g)*128 + (t-128)];
    __syncthreads();
    float a = fc1b[t];
    for (int k=0;k<256;k++) a += xc[k]*fc1W[k*256 + t];
    y1[t] = lrelu01(a);
    __syncthreads();
    if (t < 64){
        float a2 = fc2b[t];
        for (int k=0;k<256;k++) a2 += y1[k]*fc2W[k*64 + t];
        y2[t] = lrelu01(a2);
    }
    __syncthreads();
    if (t == 0){
        float z = outb[0];
        for (int k=0;k<64;k++) z += y2[k]*outW[k];
        out[g] = 1.f/(1.f + expf(-z));
    }
}

extern "C" void kernel_launch(void* const* d_in, const int* in_sizes, int n_in,
                              void* d_out, int out_size, void* d_ws, size_t ws_size,
                              hipStream_t stream){
    const float* X0 = (const float*)d_in[0];
    const float* X1 = (const float*)d_in[5];
    const int *e10=(const int*)d_in[1], *e20=(const int*)d_in[2], *e30=(const int*)d_in[3];
    const int *e11=(const int*)d_in[6], *e21=(const int*)d_in[7], *e31=(const int*)d_in[8];
    const int *b0=(const int*)d_in[4], *b1=(const int*)d_in[9];
    const float *W0=(const float*)d_in[10], *W1=(const float*)d_in[16];
    const float *as0=(const float*)d_in[11], *ad0=(const float*)d_in[12];
    const float *as1=(const float*)d_in[17], *ad1=(const float*)d_in[18];
    const float *bv0=(const float*)d_in[13], *bv1=(const float*)d_in[19];
    const float *pW0=(const float*)d_in[14], *pb0=(const float*)d_in[15];
    const float *pW1=(const float*)d_in[20], *pb1=(const float*)d_in[21];
    const float *fc1W=(const float*)d_in[22], *fc1b=(const float*)d_in[23];
    const float *fc2W=(const float*)d_in[24], *fc2b=(const float*)d_in[25];
    const float *outW=(const float*)d_in[26], *outb=(const float*)d_in[27];
    float* out = (float*)d_out;

    char* ws = (char*)d_ws;
    size_t o = 0;
    auto alloc = [&](size_t bytes)->char*{ char* p = ws + o; o += (bytes + 511) & ~(size_t)511; return p; };
    unsigned char* H8 = (unsigned char*)alloc((size_t)2*N_NODES*D_HID);
    float*  hacc  = (float*) alloc((size_t)2*N_NODES*D_HID*4);
    float*  als   = (float*) alloc((size_t)2*N_NODES*4);
    float*  ald   = (float*) alloc((size_t)2*N_NODES*4);
    int*    offs3 = (int*)   alloc((size_t)2*(NT3+1)*4);
    int*    esrc3 = (int*)   alloc((size_t)2*3*N_EDGES*4);
    int*    gcur  = (int*)   alloc((size_t)2*NB*4);
    uint*   pairs = (uint*)  alloc((size_t)2*NB*CAP*4);
    ushort* Wt    = (ushort*)alloc((size_t)2*D_HID*F_IN*2);
    float*  xb    = (float*) alloc((size_t)2*N_GRAPH*D_HID*4);

    k_prep    <<<1025, 256, 0, stream>>>(W0, W1, Wt, gcur);
    k_gemm    <<<dim3((N_NODES+BM-1)/BM, 2), 256, 0, stream>>>(X0, X1, Wt, as0, ad0, as1, ad1, H8, als, ald);
    k_bin     <<<2*NBIN_PB, 256, 0, stream>>>(e10, e20, e30, e11, e21, e31, gcur, pairs);
    k_localcsr<<<2*NB, 256, 0, stream>>>(gcur, pairs, offs3, esrc3);
    k_gat3    <<<dim3((N_NODES+3)/4, 2), 256, 0, stream>>>(offs3, esrc3, als, ald, (const uint2*)H8, bv0, bv1, hacc);
    k_pool_fc <<<dim3(N_GRAPH, 2), 256, 0, stream>>>(hacc, b0, b1, pW0, pb0, pW1, pb1, xb);
    k_final   <<<N_GRAPH, 256, 0, stream>>>(xb, fc1W, fc1b, fc2W, fc2b, outW, outb, out);
}